// Round 10
// baseline (52.117 us; speedup 1.0000x reference)
//
#include <hip/hip_runtime.h>
#include <hip/hip_bf16.h>

typedef __attribute__((ext_vector_type(8))) short bf16x8;
typedef __attribute__((ext_vector_type(4))) float f32x4;

#define BN 128
#define BK 64

// ---------------- fused prep: x cast + LDS-tiled weight transposes ----------------
// grid: [0,4096) x-cast | [4096,4288) WqkvT (8x24 tiles) | [4288,4352) WprojT (8x8)
// q-columns of Wqkv (col < 512) pre-scaled by 0.125 (= hd^-0.5, exact pow2).

__global__ __launch_bounds__(256) void prep_kernel(
    const float* __restrict__ x, const float* __restrict__ Wqkv,
    const float* __restrict__ Wproj, __hip_bfloat16* __restrict__ xb,
    __hip_bfloat16* __restrict__ wqkvT, __hip_bfloat16* __restrict__ wprojT) {
  int bid = blockIdx.x;
  int tid = threadIdx.x;
  if (bid < 4096) {
    int i = bid * 256 + tid;  // < 1048576
    const float4 v = reinterpret_cast<const float4*>(x)[i];
    union { unsigned short us[4]; uint2 u2; } o;
    __hip_bfloat16 h0 = __float2bfloat16(v.x), h1 = __float2bfloat16(v.y);
    __hip_bfloat16 h2 = __float2bfloat16(v.z), h3 = __float2bfloat16(v.w);
    o.us[0] = *reinterpret_cast<unsigned short*>(&h0);
    o.us[1] = *reinterpret_cast<unsigned short*>(&h1);
    o.us[2] = *reinterpret_cast<unsigned short*>(&h2);
    o.us[3] = *reinterpret_cast<unsigned short*>(&h3);
    *reinterpret_cast<uint2*>(xb + (size_t)i * 4) = o.u2;
    return;
  }
  __shared__ float t[64][65];
  const float* src;
  __hip_bfloat16* dst;
  int C;
  int rb, cb;
  bool isqkv;
  if (bid < 4288) {
    int b = bid - 4096;  // 8 row-tiles x 24 col-tiles
    rb = b & 7; cb = b >> 3;
    src = Wqkv; dst = wqkvT; C = 1536; isqkv = true;
  } else {
    int b = bid - 4288;  // 8 x 8
    rb = b & 7; cb = b >> 3;
    src = Wproj; dst = wprojT; C = 512; isqkv = false;
  }
  int r0 = rb * 64, c0 = cb * 64;
  int ty = tid >> 6, tx = tid & 63;
#pragma unroll
  for (int i = 0; i < 16; ++i) {
    int r = ty * 16 + i;
    t[r][tx] = src[(size_t)(r0 + r) * C + c0 + tx];
  }
  __syncthreads();
  float sc = (isqkv && c0 < 512) ? 0.125f : 1.0f;  // c0 tile-uniform: q cols [0,512)
#pragma unroll
  for (int i = 0; i < 16; ++i) {
    int cr = ty * 16 + i;
    dst[(size_t)(c0 + cr) * 512 + r0 + tx] = __float2bfloat16(t[tx][cr] * sc);
  }
}

// ---------------- GEMM1: [qk | vt] = xb @ WqkvT^T ----------------
// 128x128 tile, single-buffer m97-style loop (R8-proven), XOR-swizzled LDS,
// XCD-bijective swizzle. Split epilogue:
//   bx < 8  (cols 0..1023   = q,k): row-major write to qk [M][1024]
//   bx >= 8 (cols 1024..1535 = v) : transpose via LDS -> vt[b][cv][n] (coalesced)
// vt gives attention's PV B-fragment as contiguous bf16x8 loads.

__global__ __launch_bounds__(256, 3) void gemm1_qkv(
    const __hip_bfloat16* __restrict__ A,   // xb [M][512] bf16
    const __hip_bfloat16* __restrict__ BT,  // wqkvT [1536][512] bf16
    __hip_bfloat16* __restrict__ qk,        // [M][1024] bf16
    __hip_bfloat16* __restrict__ vt,        // [4][512][2048] bf16
    int M, int K) {
  __shared__ union {
    struct { __hip_bfloat16 a[128 * BK]; __hip_bfloat16 b[128 * BK]; } s;  // 32 KB
    __hip_bfloat16 t[128 * 136];  // transpose stage (34 KB, stride-136 pad)
  } sh;

  const int tid = threadIdx.x;
  const int lane = tid & 63;
  const int wid = tid >> 6;

  const int nwg = gridDim.x * gridDim.y;  // 768
  const int lin = blockIdx.y * gridDim.x + blockIdx.x;
  const int cpx = nwg >> 3;
  const int swz = (lin & 7) * cpx + (lin >> 3);
  const int bx = swz % gridDim.x;
  const int by = swz / gridDim.x;

  const int row0 = by * 128;
  const int col0 = bx * BN;
  const int wrow = (wid >> 1) * 64;
  const int wcol = (wid & 1) * 64;
  const int r15 = lane & 15;
  const int g = lane >> 4;

  f32x4 acc[4][4] = {};

  const int NT = K / BK;
  for (int t = 0; t < NT; ++t) {
    const int k0 = t * BK;
#pragma unroll
    for (int i = 0; i < 4; ++i) {
      int c = wid * 256 + i * 64 + lane;
      int trow = c >> 3;
      int tcol = ((c & 7) ^ (trow & 7)) * 8;  // inverse-swizzled source
      const __hip_bfloat16* ga = A + (size_t)(row0 + trow) * K + k0 + tcol;
      const __hip_bfloat16* gb = BT + (size_t)(col0 + trow) * K + k0 + tcol;
      __builtin_amdgcn_global_load_lds(
          (const __attribute__((address_space(1))) void*)ga,
          (__attribute__((address_space(3))) void*)(&sh.s.a[0] + (size_t)(wid * 256 + i * 64) * 8),
          16, 0, 0);
      __builtin_amdgcn_global_load_lds(
          (const __attribute__((address_space(1))) void*)gb,
          (__attribute__((address_space(3))) void*)(&sh.s.b[0] + (size_t)(wid * 256 + i * 64) * 8),
          16, 0, 0);
    }
    __syncthreads();

    const bf16x8* Av = reinterpret_cast<const bf16x8*>(&sh.s.a[0]);
    const bf16x8* Bv = reinterpret_cast<const bf16x8*>(&sh.s.b[0]);
#pragma unroll
    for (int kc = 0; kc < 2; ++kc) {
      bf16x8 af[4], bfr[4];
#pragma unroll
      for (int m = 0; m < 4; ++m) {
        int ra = wrow + m * 16 + r15;
        af[m] = Av[ra * 8 + ((kc * 4 + g) ^ (ra & 7))];
      }
#pragma unroll
      for (int n = 0; n < 4; ++n) {
        int rb = wcol + n * 16 + r15;
        bfr[n] = Bv[rb * 8 + ((kc * 4 + g) ^ (rb & 7))];
      }
#pragma unroll
      for (int m = 0; m < 4; ++m)
#pragma unroll
        for (int n = 0; n < 4; ++n)
          acc[m][n] = __builtin_amdgcn_mfma_f32_16x16x32_bf16(af[m], bfr[n], acc[m][n], 0, 0, 0);
    }
    __syncthreads();
  }

  if (bx < 8) {
    // q,k block: row-major, ldc = 1024
    const int orow_base = row0 + wrow + g * 4;
#pragma unroll
    for (int m = 0; m < 4; ++m)
#pragma unroll
      for (int r = 0; r < 4; ++r) {
        int row = orow_base + m * 16 + r;
#pragma unroll
        for (int n = 0; n < 4; ++n) {
          int col = col0 + wcol + n * 16 + r15;
          qk[(size_t)row * 1024 + col] = __float2bfloat16(acc[m][n][r]);
        }
      }
  } else {
    // V block: 128x128 transpose through LDS (safe: loop ended with barrier)
#pragma unroll
    for (int m = 0; m < 4; ++m)
#pragma unroll
      for (int r = 0; r < 4; ++r) {
        int rl = wrow + m * 16 + g * 4 + r;
#pragma unroll
        for (int n = 0; n < 4; ++n) {
          int cl = wcol + n * 16 + r15;
          sh.t[(size_t)cl * 136 + rl] = __float2bfloat16(acc[m][n][r]);
        }
      }
    __syncthreads();
    const int b = row0 >> 11;          // batch
    const int rloc = row0 & 2047;      // row within batch
    const int cv0 = col0 - 1024;       // v-col base (0..384)
    const int colL = tid >> 1;
    const int rh = (tid & 1) * 64;
    __hip_bfloat16* dst = vt + ((size_t)b * 512 + cv0 + colL) * 2048 + rloc + rh;
#pragma unroll
    for (int e = 0; e < 8; ++e) {
      bf16x8 v = *reinterpret_cast<const bf16x8*>(&sh.t[(size_t)colL * 136 + rh + e * 8]);
      *reinterpret_cast<bf16x8*>(dst + e * 8) = v;
    }
  }
}

// ---------------- bf16 MFMA GEMM (GEMM2): C = A @ BT^T + bias ----------------
// 64x128 tile, 2-phase double-buffered, XOR-swizzled LDS, XCD-bijective swizzle.

__global__ __launch_bounds__(256, 2) void gemm2_bt(
    const __hip_bfloat16* __restrict__ A, const __hip_bfloat16* __restrict__ BT,
    float* __restrict__ Cout, const float* __restrict__ bias, int M, int N, int K) {
  constexpr int TBM = 64;
  constexpr int MREP = 2;
  __shared__ __hip_bfloat16 As[2][TBM * BK];
  __shared__ __hip_bfloat16 Bs[2][BN * BK];

  const int tid = threadIdx.x;
  const int lane = tid & 63;
  const int wid = tid >> 6;

  const int nwg = gridDim.x * gridDim.y;
  const int lin = blockIdx.y * gridDim.x + blockIdx.x;
  const int cpx = nwg >> 3;
  const int swz = (lin & 7) * cpx + (lin >> 3);
  const int bx = swz % gridDim.x;
  const int by = swz / gridDim.x;

  const int row0 = by * TBM;
  const int col0 = bx * BN;
  const int wrow = (wid >> 1) * (TBM / 2);
  const int wcol = (wid & 1) * 64;
  const int r15 = lane & 15;
  const int g = lane >> 4;

  f32x4 acc[MREP][4] = {};

  auto stage = [&](int buf, int k0) {
#pragma unroll
    for (int i = 0; i < 4; ++i) {
      int c = wid * 256 + i * 64 + lane;
      int trow = c >> 3;
      int tcol = ((c & 7) ^ (trow & 7)) * 8;
      const __hip_bfloat16* gb = BT + (size_t)(col0 + trow) * K + k0 + tcol;
      __builtin_amdgcn_global_load_lds(
          (const __attribute__((address_space(1))) void*)gb,
          (__attribute__((address_space(3))) void*)(&Bs[buf][0] + (size_t)(wid * 256 + i * 64) * 8),
          16, 0, 0);
    }
#pragma unroll
    for (int i = 0; i < TBM / 32; ++i) {
      int c = wid * (TBM * 2) + i * 64 + lane;
      int trow = c >> 3;
      int tcol = ((c & 7) ^ (trow & 7)) * 8;
      const __hip_bfloat16* ga = A + (size_t)(row0 + trow) * K + k0 + tcol;
      __builtin_amdgcn_global_load_lds(
          (const __attribute__((address_space(1))) void*)ga,
          (__attribute__((address_space(3))) void*)(&As[buf][0] + (size_t)(wid * (TBM * 2) + i * 64) * 8),
          16, 0, 0);
    }
  };

  auto compute = [&](int buf) {
    const bf16x8* Av = reinterpret_cast<const bf16x8*>(&As[buf][0]);
    const bf16x8* Bv = reinterpret_cast<const bf16x8*>(&Bs[buf][0]);
#pragma unroll
    for (int kc = 0; kc < 2; ++kc) {
      bf16x8 af[MREP], bfr[4];
#pragma unroll
      for (int m = 0; m < MREP; ++m) {
        int ra = wrow + m * 16 + r15;
        af[m] = Av[ra * 8 + ((kc * 4 + g) ^ (ra & 7))];
      }
#pragma unroll
      for (int n = 0; n < 4; ++n) {
        int rb = wcol + n * 16 + r15;
        bfr[n] = Bv[rb * 8 + ((kc * 4 + g) ^ (rb & 7))];
      }
#pragma unroll
      for (int m = 0; m < MREP; ++m)
#pragma unroll
        for (int n = 0; n < 4; ++n)
          acc[m][n] = __builtin_amdgcn_mfma_f32_16x16x32_bf16(af[m], bfr[n], acc[m][n], 0, 0, 0);
    }
  };

  const int NT = K / BK;
  stage(0, 0);
  __syncthreads();
  int cur = 0;
  for (int t = 0; t < NT; ++t) {
    if (t + 1 < NT) stage(cur ^ 1, (t + 1) * BK);
    compute(cur);
    if (t + 1 < NT) {
      __syncthreads();
      cur ^= 1;
    }
  }

  const int orow_base = row0 + wrow + g * 4;
#pragma unroll
  for (int m = 0; m < MREP; ++m)
#pragma unroll
    for (int r = 0; r < 4; ++r) {
      int row = orow_base + m * 16 + r;
#pragma unroll
      for (int n = 0; n < 4; ++n) {
        int col = col0 + wcol + n * 16 + r15;
        Cout[(size_t)row * N + col] = acc[m][n][r] + bias[col];
      }
    }
}

// ---------------- MFMA banded local attention ----------------
// qk: [B*N][1024] bf16 (q pre-scaled; k at +512; head offset h*64)
// vt: [B][512][2048] bf16 (vt[b][h*64+d][n])
// att: [B*N][512] bf16;  one wave per (b, h, 16-row i-tile)
__global__ __launch_bounds__(256) void attn_mfma_kernel(
    const __hip_bfloat16* __restrict__ qk, const __hip_bfloat16* __restrict__ vt,
    __hip_bfloat16* __restrict__ att) {
  const int N = 2048;
  int unit = blockIdx.x * 4 + (threadIdx.x >> 6);
  int lane = threadIdx.x & 63;
  int b = unit >> 10;
  int h = (unit >> 7) & 7;
  int tile = unit & 127;
  int i0 = tile * 16;
  int jbase = i0 - 8;
  if (jbase < 0) jbase = 0;
  if (jbase > N - 32) jbase = N - 32;

  const int c = lane & 15;
  const int g = lane >> 4;

  size_t qrow = (size_t)(b * N + i0 + c) * 1024 + h * 64;
  bf16x8 qf[2];
  qf[0] = *reinterpret_cast<const bf16x8*>(qk + qrow + g * 8);
  qf[1] = *reinterpret_cast<const bf16x8*>(qk + qrow + 32 + g * 8);

  bf16x8 kf[2][2];
#pragma unroll
  for (int jblk = 0; jblk < 2; ++jblk) {
    size_t krow = (size_t)(b * N + jbase + jblk * 16 + c) * 1024 + 512 + h * 64;
    kf[jblk][0] = *reinterpret_cast<const bf16x8*>(qk + krow + g * 8);
    kf[jblk][1] = *reinterpret_cast<const bf16x8*>(qk + krow + 32 + g * 8);
  }

  // V fragments: contiguous bf16x8 from vt (8 consecutive n at fixed d)
  const __hip_bfloat16* vtb = vt + ((size_t)b * 512 + h * 64) * 2048;
  bf16x8 vf[4];
#pragma unroll
  for (int dblk = 0; dblk < 4; ++dblk)
    vf[dblk] = *reinterpret_cast<const bf16x8*>(
        vtb + (size_t)(dblk * 16 + c) * 2048 + jbase + g * 8);

  f32x4 sT[2] = {};
#pragma unroll
  for (int jblk = 0; jblk < 2; ++jblk)
#pragma unroll
    for (int kc = 0; kc < 2; ++kc)
      sT[jblk] = __builtin_amdgcn_mfma_f32_16x16x32_bf16(kf[jblk][kc], qf[kc], sT[jblk], 0, 0, 0);

  float s[2][4];
  const int i = i0 + c;
#pragma unroll
  for (int blk = 0; blk < 2; ++blk)
#pragma unroll
    for (int r = 0; r < 4; ++r) {
      int j = jbase + blk * 16 + g * 4 + r;
      int d = i - j;
      s[blk][r] = (d <= 8 && d >= -8) ? sT[blk][r] : -1e30f;
    }

  float m = -1e30f;
#pragma unroll
  for (int blk = 0; blk < 2; ++blk)
#pragma unroll
    for (int r = 0; r < 4; ++r) m = fmaxf(m, s[blk][r]);
  m = fmaxf(m, __shfl_xor(m, 16));
  m = fmaxf(m, __shfl_xor(m, 32));

  float p[2][4];
  float den = 0.f;
#pragma unroll
  for (int blk = 0; blk < 2; ++blk)
#pragma unroll
    for (int r = 0; r < 4; ++r) {
      p[blk][r] = __expf(s[blk][r] - m);
      den += p[blk][r];
    }
  den += __shfl_xor(den, 16);
  den += __shfl_xor(den, 32);
  float inv = 1.0f / den;
#pragma unroll
  for (int blk = 0; blk < 2; ++blk)
#pragma unroll
    for (int r = 0; r < 4; ++r) p[blk][r] *= inv;

  auto pack2 = [](float a, float bb) -> unsigned int {
    __hip_bfloat16 lo = __float2bfloat16(a), hi = __float2bfloat16(bb);
    unsigned short ls = *reinterpret_cast<unsigned short*>(&lo);
    unsigned short hs = *reinterpret_cast<unsigned short*>(&hi);
    return (unsigned int)ls | ((unsigned int)hs << 16);
  };
  unsigned int w00 = pack2(p[0][0], p[0][1]);
  unsigned int w01 = pack2(p[0][2], p[0][3]);
  unsigned int w10 = pack2(p[1][0], p[1][1]);
  unsigned int w11 = pack2(p[1][2], p[1][3]);

  int L1 = ((g & 1) << 5) | c;
  int L2 = L1 + 16;
  unsigned int a0 = (unsigned int)__shfl((int)w00, L1);
  unsigned int b0 = (unsigned int)__shfl((int)w10, L1);
  unsigned int a1 = (unsigned int)__shfl((int)w01, L1);
  unsigned int b1 = (unsigned int)__shfl((int)w11, L1);
  unsigned int a2 = (unsigned int)__shfl((int)w00, L2);
  unsigned int b2 = (unsigned int)__shfl((int)w10, L2);
  unsigned int a3 = (unsigned int)__shfl((int)w01, L2);
  unsigned int b3 = (unsigned int)__shfl((int)w11, L2);
  bool hiblk = (g >> 1) != 0;
  union { unsigned int u[4]; bf16x8 v; } pf;
  pf.u[0] = hiblk ? b0 : a0;
  pf.u[1] = hiblk ? b1 : a1;
  pf.u[2] = hiblk ? b2 : a2;
  pf.u[3] = hiblk ? b3 : a3;

  f32x4 o[4];
#pragma unroll
  for (int dblk = 0; dblk < 4; ++dblk) {
    f32x4 z = {};
    o[dblk] = __builtin_amdgcn_mfma_f32_16x16x32_bf16(pf.v, vf[dblk], z, 0, 0, 0);
  }

#pragma unroll
  for (int dblk = 0; dblk < 4; ++dblk)
#pragma unroll
    for (int r = 0; r < 4; ++r)
      att[(size_t)(b * N + i0 + 4 * g + r) * 512 + h * 64 + dblk * 16 + c] =
          __float2bfloat16(o[dblk][r]);
}

// ---------------- launch ----------------

extern "C" void kernel_launch(void* const* d_in, const int* in_sizes, int n_in,
                              void* d_out, int out_size, void* d_ws, size_t ws_size,
                              hipStream_t stream) {
  const float* x = (const float*)d_in[0];      // [4,2048,512]
  const float* Wqkv = (const float*)d_in[1];   // [512,1536]
  const float* Wproj = (const float*)d_in[2];  // [512,512]
  const float* bproj = (const float*)d_in[3];  // [512]
  float* out = (float*)d_out;                  // [4,2048,512]
  (void)in_sizes; (void)n_in; (void)out_size; (void)ws_size;

  const int M = 8192;  // B*N
  const int C = 512;
  const int N3 = 1536;

  size_t off = 0;
  auto alloc = [&](size_t bytes) {
    void* p = (char*)d_ws + off;
    off += (bytes + 255) & ~(size_t)255;
    return p;
  };
  __hip_bfloat16* xb = (__hip_bfloat16*)alloc((size_t)M * C * 2);       // 8 MB
  __hip_bfloat16* wqkvT = (__hip_bfloat16*)alloc((size_t)N3 * C * 2);   // 1.5 MB
  __hip_bfloat16* wprojT = (__hip_bfloat16*)alloc((size_t)C * C * 2);   // 0.5 MB
  __hip_bfloat16* qkb = (__hip_bfloat16*)alloc((size_t)M * 1024 * 2);   // 16 MB
  __hip_bfloat16* vtb = (__hip_bfloat16*)alloc((size_t)4 * 512 * 2048 * 2);  // 8 MB
  __hip_bfloat16* attb = (__hip_bfloat16*)alloc((size_t)M * C * 2);     // 8 MB

  // fused prep: x cast (4096) + WqkvT tiles (192, q-scaled) + WprojT tiles (64)
  prep_kernel<<<4352, 256, 0, stream>>>(x, Wqkv, Wproj, xb, wqkvT, wprojT);

  // GEMM1: qk + vt = xb @ Wqkv  (768 blocks, 128x128, single-buffer, split epilogue)
  gemm1_qkv<<<dim3(N3 / BN, M / 128), 256, 0, stream>>>(xb, wqkvT, qkb, vtb, M, C);

  // banded attention (MFMA): 4096 waves, 4 per block
  attn_mfma_kernel<<<1024, 256, 0, stream>>>(qkb, vtb, attb);

  // GEMM2: out = att @ Wproj + bproj  (512 blocks, 64x128, double-buffered)
  gemm2_bt<<<dim3(C / BN, M / 64), 256, 0, stream>>>(attb, wprojT, out, bproj, M, C, C);
}

// Round 11
// 49.518 us; speedup vs baseline: 1.0525x; 1.0525x over previous
//
#include <hip/hip_runtime.h>
#include <hip/hip_bf16.h>

typedef __attribute__((ext_vector_type(8))) short bf16x8;
typedef __attribute__((ext_vector_type(4))) float f32x4;

#define BN 128
#define BK 64

// ---------------- fused prep: x cast + LDS-tiled weight transposes ----------------
// grid: [0,4096) x-cast | [4096,4288) WqkvT (8x24 tiles) | [4288,4352) WprojT (8x8)
// q-columns of Wqkv (col < 512) pre-scaled by 0.125 (= hd^-0.5, exact pow2).

__global__ __launch_bounds__(256) void prep_kernel(
    const float* __restrict__ x, const float* __restrict__ Wqkv,
    const float* __restrict__ Wproj, __hip_bfloat16* __restrict__ xb,
    __hip_bfloat16* __restrict__ wqkvT, __hip_bfloat16* __restrict__ wprojT) {
  int bid = blockIdx.x;
  int tid = threadIdx.x;
  if (bid < 4096) {
    int i = bid * 256 + tid;  // < 1048576
    const float4 v = reinterpret_cast<const float4*>(x)[i];
    union { unsigned short us[4]; uint2 u2; } o;
    __hip_bfloat16 h0 = __float2bfloat16(v.x), h1 = __float2bfloat16(v.y);
    __hip_bfloat16 h2 = __float2bfloat16(v.z), h3 = __float2bfloat16(v.w);
    o.us[0] = *reinterpret_cast<unsigned short*>(&h0);
    o.us[1] = *reinterpret_cast<unsigned short*>(&h1);
    o.us[2] = *reinterpret_cast<unsigned short*>(&h2);
    o.us[3] = *reinterpret_cast<unsigned short*>(&h3);
    *reinterpret_cast<uint2*>(xb + (size_t)i * 4) = o.u2;
    return;
  }
  __shared__ float t[64][65];
  const float* src;
  __hip_bfloat16* dst;
  int C;
  int rb, cb;
  bool isqkv;
  if (bid < 4288) {
    int b = bid - 4096;  // 8 row-tiles x 24 col-tiles
    rb = b & 7; cb = b >> 3;
    src = Wqkv; dst = wqkvT; C = 1536; isqkv = true;
  } else {
    int b = bid - 4288;  // 8 x 8
    rb = b & 7; cb = b >> 3;
    src = Wproj; dst = wprojT; C = 512; isqkv = false;
  }
  int r0 = rb * 64, c0 = cb * 64;
  int ty = tid >> 6, tx = tid & 63;
#pragma unroll
  for (int i = 0; i < 16; ++i) {
    int r = ty * 16 + i;
    t[r][tx] = src[(size_t)(r0 + r) * C + c0 + tx];
  }
  __syncthreads();
  float sc = (isqkv && c0 < 512) ? 0.125f : 1.0f;  // c0 tile-uniform: q cols [0,512)
#pragma unroll
  for (int i = 0; i < 16; ++i) {
    int cr = ty * 16 + i;
    dst[(size_t)(c0 + cr) * 512 + r0 + tx] = __float2bfloat16(t[tx][cr] * sc);
  }
}

// ---------------- bf16 MFMA GEMM:  C[M,N] = A[M,K] @ BT[N,K]^T (+bias) ----------------
// TBM x 128 tile. DBUF=1: 2-phase double-buffered. DBUF=0: m97-style single-buffer
// 2-barrier loop (more blocks/CU, implicit wave overlap — R8-proven).
// XOR-swizzled LDS (k-chunk ^= row&7) with inverse-swizzled global source (both sides);
// XCD-bijective block swizzle (grid % 8 == 0 for all our shapes).

template <int TBM, int DBUF, int OUT_BF16, int HAS_BIAS>
__global__ __launch_bounds__(256, DBUF ? 2 : (TBM == 32 ? 4 : 3)) void gemm_bt(
    const __hip_bfloat16* __restrict__ A,   // [M][K] row-major bf16
    const __hip_bfloat16* __restrict__ BT,  // [N][K] row-major bf16
    void* __restrict__ Cout,                // [M][N] bf16 or fp32
    const float* __restrict__ bias,         // [N] fp32 (if HAS_BIAS)
    int M, int N, int K) {
  constexpr int MREP = TBM / 32;
  constexpr int NBUF = DBUF ? 2 : 1;
  __shared__ __hip_bfloat16 As[NBUF][TBM * BK];
  __shared__ __hip_bfloat16 Bs[NBUF][BN * BK];

  const int tid = threadIdx.x;
  const int lane = tid & 63;
  const int wid = tid >> 6;

  const int nwg = gridDim.x * gridDim.y;
  const int lin = blockIdx.y * gridDim.x + blockIdx.x;
  const int cpx = nwg >> 3;  // nwg % 8 == 0 guaranteed by launch
  const int swz = (lin & 7) * cpx + (lin >> 3);
  const int bx = swz % gridDim.x;
  const int by = swz / gridDim.x;

  const int row0 = by * TBM;
  const int col0 = bx * BN;
  const int wrow = (wid >> 1) * (TBM / 2);
  const int wcol = (wid & 1) * 64;
  const int r15 = lane & 15;
  const int g = lane >> 4;

  f32x4 acc[MREP][4] = {};

  auto stage = [&](int buf, int k0) {
#pragma unroll
    for (int i = 0; i < 4; ++i) {
      int c = wid * 256 + i * 64 + lane;
      int trow = c >> 3;
      int tcol = ((c & 7) ^ (trow & 7)) * 8;  // inverse-swizzled source
      const __hip_bfloat16* gb = BT + (size_t)(col0 + trow) * K + k0 + tcol;
      __builtin_amdgcn_global_load_lds(
          (const __attribute__((address_space(1))) void*)gb,
          (__attribute__((address_space(3))) void*)(&Bs[buf][0] + (size_t)(wid * 256 + i * 64) * 8),
          16, 0, 0);
    }
#pragma unroll
    for (int i = 0; i < TBM / 32; ++i) {
      int c = wid * (TBM * 2) + i * 64 + lane;
      int trow = c >> 3;
      int tcol = ((c & 7) ^ (trow & 7)) * 8;
      const __hip_bfloat16* ga = A + (size_t)(row0 + trow) * K + k0 + tcol;
      __builtin_amdgcn_global_load_lds(
          (const __attribute__((address_space(1))) void*)ga,
          (__attribute__((address_space(3))) void*)(&As[buf][0] + (size_t)(wid * (TBM * 2) + i * 64) * 8),
          16, 0, 0);
    }
  };

  auto compute = [&](int buf) {
    const bf16x8* Av = reinterpret_cast<const bf16x8*>(&As[buf][0]);
    const bf16x8* Bv = reinterpret_cast<const bf16x8*>(&Bs[buf][0]);
#pragma unroll
    for (int kc = 0; kc < 2; ++kc) {
      bf16x8 af[MREP], bfr[4];
#pragma unroll
      for (int m = 0; m < MREP; ++m) {
        int ra = wrow + m * 16 + r15;
        af[m] = Av[ra * 8 + ((kc * 4 + g) ^ (ra & 7))];
      }
#pragma unroll
      for (int n = 0; n < 4; ++n) {
        int rb = wcol + n * 16 + r15;
        bfr[n] = Bv[rb * 8 + ((kc * 4 + g) ^ (rb & 7))];
      }
#pragma unroll
      for (int m = 0; m < MREP; ++m)
#pragma unroll
        for (int n = 0; n < 4; ++n)
          acc[m][n] = __builtin_amdgcn_mfma_f32_16x16x32_bf16(af[m], bfr[n], acc[m][n], 0, 0, 0);
    }
  };

  const int NT = K / BK;
  if constexpr (DBUF) {
    stage(0, 0);
    __syncthreads();
    int cur = 0;
    for (int t = 0; t < NT; ++t) {
      if (t + 1 < NT) stage(cur ^ 1, (t + 1) * BK);
      compute(cur);
      if (t + 1 < NT) {
        __syncthreads();
        cur ^= 1;
      }
    }
  } else {
    for (int t = 0; t < NT; ++t) {
      stage(0, t * BK);
      __syncthreads();
      compute(0);
      __syncthreads();
    }
  }

  // epilogue: D row = g*4 + reg, col = r15 within each 16x16 tile
  const int orow_base = row0 + wrow + g * 4;
#pragma unroll
  for (int m = 0; m < MREP; ++m)
#pragma unroll
    for (int r = 0; r < 4; ++r) {
      int row = orow_base + m * 16 + r;
#pragma unroll
      for (int n = 0; n < 4; ++n) {
        int col = col0 + wcol + n * 16 + r15;
        float v = acc[m][n][r];
        if (HAS_BIAS) v += bias[col];
        if (OUT_BF16)
          ((__hip_bfloat16*)Cout)[(size_t)row * N + col] = __float2bfloat16(v);
        else
          ((float*)Cout)[(size_t)row * N + col] = v;
      }
    }
}

// ---------------- MFMA banded local attention ----------------
// qkv: [B*N][1536] bf16 (q pre-scaled by 0.125; k at +512, v at +1024; head offset h*64)
// att: [B*N][512] bf16;  one wave per (b, h, 16-row i-tile)
__global__ __launch_bounds__(256) void attn_mfma_kernel(
    const __hip_bfloat16* __restrict__ qkv, __hip_bfloat16* __restrict__ att) {
  const int N = 2048;
  int unit = blockIdx.x * 4 + (threadIdx.x >> 6);
  int lane = threadIdx.x & 63;
  int b = unit >> 10;
  int h = (unit >> 7) & 7;
  int tile = unit & 127;
  int i0 = tile * 16;
  int jbase = i0 - 8;
  if (jbase < 0) jbase = 0;
  if (jbase > N - 32) jbase = N - 32;

  const int c = lane & 15;
  const int g = lane >> 4;

  size_t qrow = (size_t)(b * N + i0 + c) * 1536 + h * 64;
  bf16x8 qf[2];
  qf[0] = *reinterpret_cast<const bf16x8*>(qkv + qrow + g * 8);
  qf[1] = *reinterpret_cast<const bf16x8*>(qkv + qrow + 32 + g * 8);

  bf16x8 kf[2][2];
#pragma unroll
  for (int jblk = 0; jblk < 2; ++jblk) {
    size_t krow = (size_t)(b * N + jbase + jblk * 16 + c) * 1536 + 512 + h * 64;
    kf[jblk][0] = *reinterpret_cast<const bf16x8*>(qkv + krow + g * 8);
    kf[jblk][1] = *reinterpret_cast<const bf16x8*>(qkv + krow + 32 + g * 8);
  }

  const __hip_bfloat16* vrow[8];
#pragma unroll
  for (int e = 0; e < 8; ++e)
    vrow[e] = qkv + (size_t)(b * N + jbase + 8 * g + e) * 1536 + 1024 + h * 64 + c;
  union VU { unsigned short us[8]; bf16x8 v; };
  VU vf[4];
#pragma unroll
  for (int dblk = 0; dblk < 4; ++dblk)
#pragma unroll
    for (int e = 0; e < 8; ++e)
      vf[dblk].us[e] = *reinterpret_cast<const unsigned short*>(vrow[e] + dblk * 16);

  f32x4 sT[2] = {};
#pragma unroll
  for (int jblk = 0; jblk < 2; ++jblk)
#pragma unroll
    for (int kc = 0; kc < 2; ++kc)
      sT[jblk] = __builtin_amdgcn_mfma_f32_16x16x32_bf16(kf[jblk][kc], qf[kc], sT[jblk], 0, 0, 0);

  float s[2][4];
  const int i = i0 + c;
#pragma unroll
  for (int blk = 0; blk < 2; ++blk)
#pragma unroll
    for (int r = 0; r < 4; ++r) {
      int j = jbase + blk * 16 + g * 4 + r;
      int d = i - j;
      s[blk][r] = (d <= 8 && d >= -8) ? sT[blk][r] : -1e30f;
    }

  float m = -1e30f;
#pragma unroll
  for (int blk = 0; blk < 2; ++blk)
#pragma unroll
    for (int r = 0; r < 4; ++r) m = fmaxf(m, s[blk][r]);
  m = fmaxf(m, __shfl_xor(m, 16));
  m = fmaxf(m, __shfl_xor(m, 32));

  float p[2][4];
  float den = 0.f;
#pragma unroll
  for (int blk = 0; blk < 2; ++blk)
#pragma unroll
    for (int r = 0; r < 4; ++r) {
      p[blk][r] = __expf(s[blk][r] - m);
      den += p[blk][r];
    }
  den += __shfl_xor(den, 16);
  den += __shfl_xor(den, 32);
  float inv = 1.0f / den;
#pragma unroll
  for (int blk = 0; blk < 2; ++blk)
#pragma unroll
    for (int r = 0; r < 4; ++r) p[blk][r] *= inv;

  auto pack2 = [](float a, float bb) -> unsigned int {
    __hip_bfloat16 lo = __float2bfloat16(a), hi = __float2bfloat16(bb);
    unsigned short ls = *reinterpret_cast<unsigned short*>(&lo);
    unsigned short hs = *reinterpret_cast<unsigned short*>(&hi);
    return (unsigned int)ls | ((unsigned int)hs << 16);
  };
  unsigned int w00 = pack2(p[0][0], p[0][1]);
  unsigned int w01 = pack2(p[0][2], p[0][3]);
  unsigned int w10 = pack2(p[1][0], p[1][1]);
  unsigned int w11 = pack2(p[1][2], p[1][3]);

  int L1 = ((g & 1) << 5) | c;
  int L2 = L1 + 16;
  unsigned int a0 = (unsigned int)__shfl((int)w00, L1);
  unsigned int b0 = (unsigned int)__shfl((int)w10, L1);
  unsigned int a1 = (unsigned int)__shfl((int)w01, L1);
  unsigned int b1 = (unsigned int)__shfl((int)w11, L1);
  unsigned int a2 = (unsigned int)__shfl((int)w00, L2);
  unsigned int b2 = (unsigned int)__shfl((int)w10, L2);
  unsigned int a3 = (unsigned int)__shfl((int)w01, L2);
  unsigned int b3 = (unsigned int)__shfl((int)w11, L2);
  bool hiblk = (g >> 1) != 0;
  union { unsigned int u[4]; bf16x8 v; } pf;
  pf.u[0] = hiblk ? b0 : a0;
  pf.u[1] = hiblk ? b1 : a1;
  pf.u[2] = hiblk ? b2 : a2;
  pf.u[3] = hiblk ? b3 : a3;

  f32x4 o[4];
#pragma unroll
  for (int dblk = 0; dblk < 4; ++dblk) {
    f32x4 z = {};
    o[dblk] = __builtin_amdgcn_mfma_f32_16x16x32_bf16(pf.v, vf[dblk].v, z, 0, 0, 0);
  }

#pragma unroll
  for (int dblk = 0; dblk < 4; ++dblk)
#pragma unroll
    for (int r = 0; r < 4; ++r)
      att[(size_t)(b * N + i0 + 4 * g + r) * 512 + h * 64 + dblk * 16 + c] =
          __float2bfloat16(o[dblk][r]);
}

// ---------------- launch ----------------

extern "C" void kernel_launch(void* const* d_in, const int* in_sizes, int n_in,
                              void* d_out, int out_size, void* d_ws, size_t ws_size,
                              hipStream_t stream) {
  const float* x = (const float*)d_in[0];      // [4,2048,512]
  const float* Wqkv = (const float*)d_in[1];   // [512,1536]
  const float* Wproj = (const float*)d_in[2];  // [512,512]
  const float* bproj = (const float*)d_in[3];  // [512]
  float* out = (float*)d_out;                  // [4,2048,512]
  (void)in_sizes; (void)n_in; (void)out_size; (void)ws_size;

  const int M = 8192;  // B*N
  const int C = 512;
  const int N3 = 1536;

  size_t off = 0;
  auto alloc = [&](size_t bytes) {
    void* p = (char*)d_ws + off;
    off += (bytes + 255) & ~(size_t)255;
    return p;
  };
  __hip_bfloat16* xb = (__hip_bfloat16*)alloc((size_t)M * C * 2);       // 8 MB
  __hip_bfloat16* wqkvT = (__hip_bfloat16*)alloc((size_t)N3 * C * 2);   // 1.5 MB
  __hip_bfloat16* wprojT = (__hip_bfloat16*)alloc((size_t)C * C * 2);   // 0.5 MB
  __hip_bfloat16* qkvb = (__hip_bfloat16*)alloc((size_t)M * N3 * 2);    // 25 MB
  __hip_bfloat16* attb = (__hip_bfloat16*)alloc((size_t)M * C * 2);     // 8 MB

  // fused prep: x cast (4096) + WqkvT tiles (192, q-scaled) + WprojT tiles (64)
  prep_kernel<<<4352, 256, 0, stream>>>(x, Wqkv, Wproj, xb, wqkvT, wprojT);

  // GEMM1: qkv = x @ Wqkv  (768 blocks, 128x128, single-buffer — R8-proven)
  gemm_bt<128, 0, 1, 0><<<dim3(N3 / BN, M / 128), 256, 0, stream>>>(
      xb, wqkvT, qkvb, nullptr, M, N3, C);

  // banded attention (MFMA): 4096 waves, 4 per block
  attn_mfma_kernel<<<1024, 256, 0, stream>>>(qkvb, attb);

  // GEMM2: out = att @ Wproj + bproj  (1024 blocks, 32x128, single-buffer, 4 blocks/CU)
  gemm_bt<32, 0, 0, 1><<<dim3(C / BN, M / 32), 256, 0, stream>>>(
      attb, wprojT, out, bproj, M, C, C);
}

// Round 12
// 49.357 us; speedup vs baseline: 1.0559x; 1.0033x over previous
//
#include <hip/hip_runtime.h>
#include <hip/hip_bf16.h>

typedef __attribute__((ext_vector_type(8))) short bf16x8;
typedef __attribute__((ext_vector_type(4))) float f32x4;

#define BN 128
#define BK 64

// ---------------- fused prep: x cast + LDS-tiled weight transposes ----------------
// grid: [0,4096) x-cast | [4096,4288) WqkvT (8x24 tiles) | [4288,4352) WprojT (8x8)
// q-columns of Wqkv (col < 512) pre-scaled by 0.125 (= hd^-0.5, exact pow2).

__global__ __launch_bounds__(256) void prep_kernel(
    const float* __restrict__ x, const float* __restrict__ Wqkv,
    const float* __restrict__ Wproj, __hip_bfloat16* __restrict__ xb,
    __hip_bfloat16* __restrict__ wqkvT, __hip_bfloat16* __restrict__ wprojT) {
  int bid = blockIdx.x;
  int tid = threadIdx.x;
  if (bid < 4096) {
    int i = bid * 256 + tid;  // < 1048576
    const float4 v = reinterpret_cast<const float4*>(x)[i];
    union { unsigned short us[4]; uint2 u2; } o;
    __hip_bfloat16 h0 = __float2bfloat16(v.x), h1 = __float2bfloat16(v.y);
    __hip_bfloat16 h2 = __float2bfloat16(v.z), h3 = __float2bfloat16(v.w);
    o.us[0] = *reinterpret_cast<unsigned short*>(&h0);
    o.us[1] = *reinterpret_cast<unsigned short*>(&h1);
    o.us[2] = *reinterpret_cast<unsigned short*>(&h2);
    o.us[3] = *reinterpret_cast<unsigned short*>(&h3);
    *reinterpret_cast<uint2*>(xb + (size_t)i * 4) = o.u2;
    return;
  }
  __shared__ float t[64][65];
  const float* src;
  __hip_bfloat16* dst;
  int C;
  int rb, cb;
  bool isqkv;
  if (bid < 4288) {
    int b = bid - 4096;  // 8 row-tiles x 24 col-tiles
    rb = b & 7; cb = b >> 3;
    src = Wqkv; dst = wqkvT; C = 1536; isqkv = true;
  } else {
    int b = bid - 4288;  // 8 x 8
    rb = b & 7; cb = b >> 3;
    src = Wproj; dst = wprojT; C = 512; isqkv = false;
  }
  int r0 = rb * 64, c0 = cb * 64;
  int ty = tid >> 6, tx = tid & 63;
#pragma unroll
  for (int i = 0; i < 16; ++i) {
    int r = ty * 16 + i;
    t[r][tx] = src[(size_t)(r0 + r) * C + c0 + tx];
  }
  __syncthreads();
  float sc = (isqkv && c0 < 512) ? 0.125f : 1.0f;  // c0 tile-uniform: q cols [0,512)
#pragma unroll
  for (int i = 0; i < 16; ++i) {
    int cr = ty * 16 + i;
    dst[(size_t)(c0 + cr) * 512 + r0 + tx] = __float2bfloat16(t[tx][cr] * sc);
  }
}

// ---------------- bf16 MFMA GEMM:  C[M,N] = A[M,K] @ BT[N,K]^T (+bias) ----------------
// TBM x 128 tile. DBUF=1: 2-phase double-buffered. DBUF=0: m97-style single-buffer
// 2-barrier loop at 4 blocks/CU (128 KB LDS total, 16 waves/CU TLP hides drains).
// XOR-swizzled LDS (k-chunk ^= row&7) with inverse-swizzled global source (both sides);
// XCD-bijective block swizzle (grid % 8 == 0 for all our shapes).

template <int TBM, int DBUF, int OUT_BF16, int HAS_BIAS>
__global__ __launch_bounds__(256, DBUF ? 2 : 4) void gemm_bt(
    const __hip_bfloat16* __restrict__ A,   // [M][K] row-major bf16
    const __hip_bfloat16* __restrict__ BT,  // [N][K] row-major bf16
    void* __restrict__ Cout,                // [M][N] bf16 or fp32
    const float* __restrict__ bias,         // [N] fp32 (if HAS_BIAS)
    int M, int N, int K) {
  constexpr int MREP = TBM / 32;
  constexpr int NBUF = DBUF ? 2 : 1;
  __shared__ __hip_bfloat16 As[NBUF][TBM * BK];
  __shared__ __hip_bfloat16 Bs[NBUF][BN * BK];

  const int tid = threadIdx.x;
  const int lane = tid & 63;
  const int wid = tid >> 6;

  const int nwg = gridDim.x * gridDim.y;
  const int lin = blockIdx.y * gridDim.x + blockIdx.x;
  const int cpx = nwg >> 3;  // nwg % 8 == 0 guaranteed by launch
  const int swz = (lin & 7) * cpx + (lin >> 3);
  const int bx = swz % gridDim.x;
  const int by = swz / gridDim.x;

  const int row0 = by * TBM;
  const int col0 = bx * BN;
  const int wrow = (wid >> 1) * (TBM / 2);
  const int wcol = (wid & 1) * 64;
  const int r15 = lane & 15;
  const int g = lane >> 4;

  f32x4 acc[MREP][4] = {};

  auto stage = [&](int buf, int k0) {
#pragma unroll
    for (int i = 0; i < 4; ++i) {
      int c = wid * 256 + i * 64 + lane;
      int trow = c >> 3;
      int tcol = ((c & 7) ^ (trow & 7)) * 8;  // inverse-swizzled source
      const __hip_bfloat16* gb = BT + (size_t)(col0 + trow) * K + k0 + tcol;
      __builtin_amdgcn_global_load_lds(
          (const __attribute__((address_space(1))) void*)gb,
          (__attribute__((address_space(3))) void*)(&Bs[buf][0] + (size_t)(wid * 256 + i * 64) * 8),
          16, 0, 0);
    }
#pragma unroll
    for (int i = 0; i < TBM / 32; ++i) {
      int c = wid * (TBM * 2) + i * 64 + lane;
      int trow = c >> 3;
      int tcol = ((c & 7) ^ (trow & 7)) * 8;
      const __hip_bfloat16* ga = A + (size_t)(row0 + trow) * K + k0 + tcol;
      __builtin_amdgcn_global_load_lds(
          (const __attribute__((address_space(1))) void*)ga,
          (__attribute__((address_space(3))) void*)(&As[buf][0] + (size_t)(wid * (TBM * 2) + i * 64) * 8),
          16, 0, 0);
    }
  };

  auto compute = [&](int buf) {
    const bf16x8* Av = reinterpret_cast<const bf16x8*>(&As[buf][0]);
    const bf16x8* Bv = reinterpret_cast<const bf16x8*>(&Bs[buf][0]);
#pragma unroll
    for (int kc = 0; kc < 2; ++kc) {
      bf16x8 af[MREP], bfr[4];
#pragma unroll
      for (int m = 0; m < MREP; ++m) {
        int ra = wrow + m * 16 + r15;
        af[m] = Av[ra * 8 + ((kc * 4 + g) ^ (ra & 7))];
      }
#pragma unroll
      for (int n = 0; n < 4; ++n) {
        int rb = wcol + n * 16 + r15;
        bfr[n] = Bv[rb * 8 + ((kc * 4 + g) ^ (rb & 7))];
      }
#pragma unroll
      for (int m = 0; m < MREP; ++m)
#pragma unroll
        for (int n = 0; n < 4; ++n)
          acc[m][n] = __builtin_amdgcn_mfma_f32_16x16x32_bf16(af[m], bfr[n], acc[m][n], 0, 0, 0);
    }
  };

  const int NT = K / BK;
  if constexpr (DBUF) {
    stage(0, 0);
    __syncthreads();
    int cur = 0;
    for (int t = 0; t < NT; ++t) {
      if (t + 1 < NT) stage(cur ^ 1, (t + 1) * BK);
      compute(cur);
      if (t + 1 < NT) {
        __syncthreads();
        cur ^= 1;
      }
    }
  } else {
    for (int t = 0; t < NT; ++t) {
      stage(0, t * BK);
      __syncthreads();
      compute(0);
      __syncthreads();
    }
  }

  // epilogue: D row = g*4 + reg, col = r15 within each 16x16 tile
  const int orow_base = row0 + wrow + g * 4;
#pragma unroll
  for (int m = 0; m < MREP; ++m)
#pragma unroll
    for (int r = 0; r < 4; ++r) {
      int row = orow_base + m * 16 + r;
#pragma unroll
      for (int n = 0; n < 4; ++n) {
        int col = col0 + wcol + n * 16 + r15;
        float v = acc[m][n][r];
        if (HAS_BIAS) v += bias[col];
        if (OUT_BF16)
          ((__hip_bfloat16*)Cout)[(size_t)row * N + col] = __float2bfloat16(v);
        else
          ((float*)Cout)[(size_t)row * N + col] = v;
      }
    }
}

// ---------------- MFMA banded local attention ----------------
// qkv: [B*N][1536] bf16 (q pre-scaled by 0.125; k at +512, v at +1024; head offset h*64)
// att: [B*N][512] bf16;  one wave per (b, h, 16-row i-tile)
__global__ __launch_bounds__(256) void attn_mfma_kernel(
    const __hip_bfloat16* __restrict__ qkv, __hip_bfloat16* __restrict__ att) {
  const int N = 2048;
  int unit = blockIdx.x * 4 + (threadIdx.x >> 6);
  int lane = threadIdx.x & 63;
  int b = unit >> 10;
  int h = (unit >> 7) & 7;
  int tile = unit & 127;
  int i0 = tile * 16;
  int jbase = i0 - 8;
  if (jbase < 0) jbase = 0;
  if (jbase > N - 32) jbase = N - 32;

  const int c = lane & 15;
  const int g = lane >> 4;

  size_t qrow = (size_t)(b * N + i0 + c) * 1536 + h * 64;
  bf16x8 qf[2];
  qf[0] = *reinterpret_cast<const bf16x8*>(qkv + qrow + g * 8);
  qf[1] = *reinterpret_cast<const bf16x8*>(qkv + qrow + 32 + g * 8);

  bf16x8 kf[2][2];
#pragma unroll
  for (int jblk = 0; jblk < 2; ++jblk) {
    size_t krow = (size_t)(b * N + jbase + jblk * 16 + c) * 1536 + 512 + h * 64;
    kf[jblk][0] = *reinterpret_cast<const bf16x8*>(qkv + krow + g * 8);
    kf[jblk][1] = *reinterpret_cast<const bf16x8*>(qkv + krow + 32 + g * 8);
  }

  const __hip_bfloat16* vrow[8];
#pragma unroll
  for (int e = 0; e < 8; ++e)
    vrow[e] = qkv + (size_t)(b * N + jbase + 8 * g + e) * 1536 + 1024 + h * 64 + c;
  union VU { unsigned short us[8]; bf16x8 v; };
  VU vf[4];
#pragma unroll
  for (int dblk = 0; dblk < 4; ++dblk)
#pragma unroll
    for (int e = 0; e < 8; ++e)
      vf[dblk].us[e] = *reinterpret_cast<const unsigned short*>(vrow[e] + dblk * 16);

  f32x4 sT[2] = {};
#pragma unroll
  for (int jblk = 0; jblk < 2; ++jblk)
#pragma unroll
    for (int kc = 0; kc < 2; ++kc)
      sT[jblk] = __builtin_amdgcn_mfma_f32_16x16x32_bf16(kf[jblk][kc], qf[kc], sT[jblk], 0, 0, 0);

  float s[2][4];
  const int i = i0 + c;
#pragma unroll
  for (int blk = 0; blk < 2; ++blk)
#pragma unroll
    for (int r = 0; r < 4; ++r) {
      int j = jbase + blk * 16 + g * 4 + r;
      int d = i - j;
      s[blk][r] = (d <= 8 && d >= -8) ? sT[blk][r] : -1e30f;
    }

  float m = -1e30f;
#pragma unroll
  for (int blk = 0; blk < 2; ++blk)
#pragma unroll
    for (int r = 0; r < 4; ++r) m = fmaxf(m, s[blk][r]);
  m = fmaxf(m, __shfl_xor(m, 16));
  m = fmaxf(m, __shfl_xor(m, 32));

  float p[2][4];
  float den = 0.f;
#pragma unroll
  for (int blk = 0; blk < 2; ++blk)
#pragma unroll
    for (int r = 0; r < 4; ++r) {
      p[blk][r] = __expf(s[blk][r] - m);
      den += p[blk][r];
    }
  den += __shfl_xor(den, 16);
  den += __shfl_xor(den, 32);
  float inv = 1.0f / den;
#pragma unroll
  for (int blk = 0; blk < 2; ++blk)
#pragma unroll
    for (int r = 0; r < 4; ++r) p[blk][r] *= inv;

  auto pack2 = [](float a, float bb) -> unsigned int {
    __hip_bfloat16 lo = __float2bfloat16(a), hi = __float2bfloat16(bb);
    unsigned short ls = *reinterpret_cast<unsigned short*>(&lo);
    unsigned short hs = *reinterpret_cast<unsigned short*>(&hi);
    return (unsigned int)ls | ((unsigned int)hs << 16);
  };
  unsigned int w00 = pack2(p[0][0], p[0][1]);
  unsigned int w01 = pack2(p[0][2], p[0][3]);
  unsigned int w10 = pack2(p[1][0], p[1][1]);
  unsigned int w11 = pack2(p[1][2], p[1][3]);

  int L1 = ((g & 1) << 5) | c;
  int L2 = L1 + 16;
  unsigned int a0 = (unsigned int)__shfl((int)w00, L1);
  unsigned int b0 = (unsigned int)__shfl((int)w10, L1);
  unsigned int a1 = (unsigned int)__shfl((int)w01, L1);
  unsigned int b1 = (unsigned int)__shfl((int)w11, L1);
  unsigned int a2 = (unsigned int)__shfl((int)w00, L2);
  unsigned int b2 = (unsigned int)__shfl((int)w10, L2);
  unsigned int a3 = (unsigned int)__shfl((int)w01, L2);
  unsigned int b3 = (unsigned int)__shfl((int)w11, L2);
  bool hiblk = (g >> 1) != 0;
  union { unsigned int u[4]; bf16x8 v; } pf;
  pf.u[0] = hiblk ? b0 : a0;
  pf.u[1] = hiblk ? b1 : a1;
  pf.u[2] = hiblk ? b2 : a2;
  pf.u[3] = hiblk ? b3 : a3;

  f32x4 o[4];
#pragma unroll
  for (int dblk = 0; dblk < 4; ++dblk) {
    f32x4 z = {};
    o[dblk] = __builtin_amdgcn_mfma_f32_16x16x32_bf16(pf.v, vf[dblk].v, z, 0, 0, 0);
  }

#pragma unroll
  for (int dblk = 0; dblk < 4; ++dblk)
#pragma unroll
    for (int r = 0; r < 4; ++r)
      att[(size_t)(b * N + i0 + 4 * g + r) * 512 + h * 64 + dblk * 16 + c] =
          __float2bfloat16(o[dblk][r]);
}

// ---------------- launch ----------------

extern "C" void kernel_launch(void* const* d_in, const int* in_sizes, int n_in,
                              void* d_out, int out_size, void* d_ws, size_t ws_size,
                              hipStream_t stream) {
  const float* x = (const float*)d_in[0];      // [4,2048,512]
  const float* Wqkv = (const float*)d_in[1];   // [512,1536]
  const float* Wproj = (const float*)d_in[2];  // [512,512]
  const float* bproj = (const float*)d_in[3];  // [512]
  float* out = (float*)d_out;                  // [4,2048,512]
  (void)in_sizes; (void)n_in; (void)out_size; (void)ws_size;

  const int M = 8192;  // B*N
  const int C = 512;
  const int N3 = 1536;

  size_t off = 0;
  auto alloc = [&](size_t bytes) {
    void* p = (char*)d_ws + off;
    off += (bytes + 255) & ~(size_t)255;
    return p;
  };
  __hip_bfloat16* xb = (__hip_bfloat16*)alloc((size_t)M * C * 2);       // 8 MB
  __hip_bfloat16* wqkvT = (__hip_bfloat16*)alloc((size_t)N3 * C * 2);   // 1.5 MB
  __hip_bfloat16* wprojT = (__hip_bfloat16*)alloc((size_t)C * C * 2);   // 0.5 MB
  __hip_bfloat16* qkvb = (__hip_bfloat16*)alloc((size_t)M * N3 * 2);    // 25 MB
  __hip_bfloat16* attb = (__hip_bfloat16*)alloc((size_t)M * C * 2);     // 8 MB

  // fused prep: x cast (4096) + WqkvT tiles (192, q-scaled) + WprojT tiles (64)
  prep_kernel<<<4352, 256, 0, stream>>>(x, Wqkv, Wproj, xb, wqkvT, wprojT);

  // GEMM1: qkv = x @ Wqkv  (768 blocks, 128x128, single-buffer, 4 blocks/CU)
  gemm_bt<128, 0, 1, 0><<<dim3(N3 / BN, M / 128), 256, 0, stream>>>(
      xb, wqkvT, qkvb, nullptr, M, N3, C);

  // banded attention (MFMA): 4096 waves, 4 per block
  attn_mfma_kernel<<<1024, 256, 0, stream>>>(qkvb, attb);

  // GEMM2: out = att @ Wproj + bproj  (1024 blocks, 32x128, single-buffer, 4 blocks/CU)
  gemm_bt<32, 0, 0, 1><<<dim3(C / BN, M / 32), 256, 0, stream>>>(
      attb, wprojT, out, bproj, M, C, C);
}